// Round 2
// baseline (1703.247 us; speedup 1.0000x reference)
//
#include <hip/hip_runtime.h>
#include <hip/hip_bf16.h>

typedef __attribute__((ext_vector_type(8))) short bf16x8;
typedef __attribute__((ext_vector_type(4))) float f32x4;
typedef __hip_bfloat16 bf16;

#define S_LEN 2048
#define HIDDEN 4096
#define NH 32
#define NKV 8
#define DH 128
#define ROTD 64
#define QKVW 6144              // fused QKV row width (32*128 + 8*128 + 8*128)
#define KOFF 4096              // K column offset in fused buffer
#define VOFF 5120              // V column offset
#define ATT_SCALE 0.08838834764831845f
#define RMS_EPS 1e-6f
#define KPITCH 136             // Ks row pitch (elems): 272B = 17*16 -> aligned, 2-way banks
#define VPITCH 72              // Vs/Ps row pitch: 144B = 9*16 -> aligned, 2-way banks

#define BAR() __builtin_amdgcn_s_barrier()
#define SB0() __builtin_amdgcn_sched_barrier(0)
#define VMCNT(n) asm volatile("s_waitcnt vmcnt(" #n ")" ::: "memory")

static __device__ __forceinline__ unsigned short f2bu(float f) {
    bf16 h = __float2bfloat16(f);
    return __builtin_bit_cast(unsigned short, h);
}

static __device__ __forceinline__ void load_lds_16(const bf16* g, bf16* l) {
    __builtin_amdgcn_global_load_lds((const __attribute__((address_space(1))) void*)g,
                                     (__attribute__((address_space(3))) void*)l, 16, 0, 0);
}

// ---------------- fp32 -> bf16 cast (vectorized float4) ----------------
__global__ __launch_bounds__(256) void cast_f32_bf16(const float* __restrict__ src,
                                                     unsigned short* __restrict__ dst, int n4) {
    int i = blockIdx.x * 256 + threadIdx.x;
    if (i >= n4) return;
    float4 v = reinterpret_cast<const float4*>(src)[i];
    ushort4 o;
    o.x = f2bu(v.x); o.y = f2bu(v.y); o.z = f2bu(v.z); o.w = f2bu(v.w);
    reinterpret_cast<ushort4*>(dst)[i] = o;
}

// ---------------- C[M,N] = A[M,K] @ B[N,K]^T ----------------
// 256x256 tile, BK=64, 8 waves (2M x 4N), 8-phase schedule with ONE-PHASE-AHEAD
// register prefetch of LDS subtiles (reads for phase i+1 issue during phase i's MFMA):
//  - reads: p0->B1(t), p1->A1(t), p2->A0(t+1), p3->B0(t+1)
//  - MFMA:  p0:Q(0,0)=A0*B0  p1:Q(0,1)=A0*B1  p2:Q(1,1)=A1*B1  p3:Q(1,0)=A1*B0
//  - staging (unchanged sigma): p0:(t+1).A1  p1:(t+2).B0  p2:(t+2).A0  p3:(t+2).B1
//  - per-phase vmcnt BEFORE barrier makes staged data cross-wave-visible post-barrier:
//      p0: vmcnt(8) [target t.B1]   p1: vmcnt(8) [t.A1]
//      p2: vmcnt(6) [t+1.A0]        p3: vmcnt(10) [t+1.B0; structurally free]
//    last 3 tiles: vmcnt(0) (guarded-off stages invalidate the counts)
//  - register sets rotate across tiles via 2-tile unroll (compile-time indices)
#define LDAH(bufi, half, dst) do {                                                      \
    const bf16* _ab = &As[bufi][half][0];                                               \
    _Pragma("unroll") for (int mf = 0; mf < 4; ++mf) {                                  \
        const int _r = arow + mf * 16;                                                  \
        _Pragma("unroll") for (int kk = 0; kk < 2; ++kk)                                \
            dst[mf][kk] = *reinterpret_cast<const bf16x8*>(                             \
                _ab + (((_r << 6) + kk * 32 + quad * 8) ^ xorv));                       \
    } } while (0)

#define LDBH(bufi, half, dst) do {                                                      \
    const bf16* _bb = &Bs[bufi][half][0];                                               \
    _Pragma("unroll") for (int nf = 0; nf < 2; ++nf) {                                  \
        const int _r = brow + nf * 16;                                                  \
        _Pragma("unroll") for (int kk = 0; kk < 2; ++kk)                                \
            dst[nf][kk] = *reinterpret_cast<const bf16x8*>(                             \
                _bb + (((_r << 6) + kk * 32 + quad * 8) ^ xorv));                       \
    } } while (0)

#define MMQ(mh, nh, A_, B_) do {                                                        \
    _Pragma("unroll") for (int mf = 0; mf < 4; ++mf)                                    \
    _Pragma("unroll") for (int nf = 0; nf < 2; ++nf)                                    \
    _Pragma("unroll") for (int kk = 0; kk < 2; ++kk)                                    \
        acc[mh][nh][mf][nf] = __builtin_amdgcn_mfma_f32_16x16x32_bf16(                  \
            A_[mf][kk], B_[nf][kk], acc[mh][nh][mf][nf], 0, 0, 0);                      \
    } while (0)

#define STAGE_A(bufi, half, tau) do {                                                   \
    const bf16* _s = Abase + (size_t)(half) * 128 * K + (size_t)(tau) * 64;             \
    load_lds_16(_s + sro0, &As[bufi][half][e0]);                                        \
    load_lds_16(_s + sro1, &As[bufi][half][e1]); } while (0)

#define STAGE_B(bufi, half, tau) do {                                                   \
    const bf16* _s = Bbase + (size_t)(half) * 128 * K + (size_t)(tau) * 64;             \
    load_lds_16(_s + sro0, &Bs[bufi][half][e0]);                                        \
    load_lds_16(_s + sro1, &Bs[bufi][half][e1]); } while (0)

#define TILE(tconst, bufc, AC, BC, AN, BN_) do {                                        \
    const int _t = (tconst);                                                            \
    const bool _tail = (_t >= NT - 3);                                                  \
    /* p0: Q(0,0) uses AC,BC (read last tile); read b1=t.B1; stage (t+1).A1 */          \
    if (_tail) { VMCNT(0); } else { VMCNT(8); }                                         \
    if (_t + 1 < NT) STAGE_A((bufc) ^ 1, 1, _t + 1);                                    \
    BAR(); SB0();                                                                       \
    LDBH(bufc, 1, b1);                                                                  \
    __builtin_amdgcn_s_setprio(1); MMQ(0, 0, AC, BC);                                   \
    __builtin_amdgcn_s_setprio(0);                                                      \
    BAR();                                                                              \
    /* p1: Q(0,1) uses AC,b1; read a1=t.A1; stage (t+2).B0 */                           \
    if (_tail) { VMCNT(0); } else { VMCNT(8); }                                         \
    if (_t + 2 < NT) STAGE_B(bufc, 0, _t + 2);                                          \
    BAR(); SB0();                                                                       \
    LDAH(bufc, 1, a1);                                                                  \
    __builtin_amdgcn_s_setprio(1); MMQ(0, 1, AC, b1);                                   \
    __builtin_amdgcn_s_setprio(0);                                                      \
    BAR();                                                                              \
    /* p2: Q(1,1) uses a1,b1; read AN=(t+1).A0; stage (t+2).A0 */                       \
    if (_tail) { VMCNT(0); } else { VMCNT(6); }                                         \
    if (_t + 2 < NT) STAGE_A(bufc, 0, _t + 2);                                          \
    BAR(); SB0();                                                                       \
    if (_t + 1 < NT) LDAH((bufc) ^ 1, 0, AN);                                           \
    __builtin_amdgcn_s_setprio(1); MMQ(1, 1, a1, b1);                                   \
    __builtin_amdgcn_s_setprio(0);                                                      \
    BAR();                                                                              \
    /* p3: Q(1,0) uses a1,BC; read BN=(t+1).B0; stage (t+2).B1 */                       \
    if (_tail) { VMCNT(0); } else { VMCNT(10); }                                        \
    if (_t + 2 < NT) STAGE_B(bufc, 1, _t + 2);                                          \
    BAR(); SB0();                                                                       \
    if (_t + 1 < NT) LDBH((bufc) ^ 1, 0, BN_);                                          \
    __builtin_amdgcn_s_setprio(1); MMQ(1, 0, a1, BC);                                   \
    __builtin_amdgcn_s_setprio(0);                                                      \
    BAR();                                                                              \
} while (0)

template <typename OutT>
__global__ __launch_bounds__(512, 2) void gemm256(const bf16* __restrict__ A,
                                                  const bf16* __restrict__ B,
                                                  OutT* __restrict__ C,
                                                  int M, int N, int K) {
    __shared__ bf16 As[2][2][128 * 64];
    __shared__ bf16 Bs[2][2][128 * 64];

    const int tid  = threadIdx.x;
    const int lane = tid & 63;
    const int lq   = lane & 15;
    const int quad = lane >> 4;
    const int wave = tid >> 6;
    const int wr   = wave >> 2;      // 0..1 (M)
    const int wc   = wave & 3;       // 0..3 (N)

    // XCD-aware block swizzle (grids here are multiples of 8)
    const int nwg = gridDim.x;
    const int cpx = nwg >> 3;
    const int wg  = (blockIdx.x & 7) * cpx + (blockIdx.x >> 3);
    const int ntn = N >> 8;
    const int m0  = (wg / ntn) << 8;
    const int n0  = (wg % ntn) << 8;

    const int NT = K >> 6;           // 64-wide K tiles (NT even, >= 4 for shapes used here)

    // ---- staging thread-constants: dest byte d -> pre-swizzled source offset o
    const int d0 = tid * 16;
    const int d1 = 8192 + tid * 16;
    const int o0 = d0 ^ (((d0 >> 7) & 7) << 4);
    const int o1 = d1 ^ (((d1 >> 7) & 7) << 4);
    const int e0 = d0 >> 1;          // LDS dest element offset (linear)
    const int e1 = d1 >> 1;
    const size_t sro0 = (size_t)((o0 >> 1) >> 6) * K + ((o0 >> 1) & 63);
    const size_t sro1 = (size_t)((o1 >> 1) >> 6) * K + ((o1 >> 1) & 63);
    const bf16* Abase = A + (size_t)m0 * K;
    const bf16* Bbase = B + (size_t)n0 * K;

    // ---- fragment read constants
    const int arow = wr * 64 + lq;   // + mf*16  (row within A half)
    const int brow = wc * 32 + lq;   // + nf*16  (row within B half)
    const int xorv = (lq & 7) << 3;  // element-offset swizzle ((row&7)<<4 bytes)

    f32x4  acc[2][2][4][2] = {};
    bf16x8 a0[4][2], a0n[4][2], a1[4][2];   // A halves: current-0, next-0, tile-local-1
    bf16x8 b0[2][2], b0n[2][2], b1[2][2];   // B halves

    // ---- prologue: stage 7 half-tiles in sigma order, make tile0 A0/B0 visible, read them
    STAGE_B(0, 0, 0); STAGE_A(0, 0, 0); STAGE_B(0, 1, 0); STAGE_A(0, 1, 0);
    STAGE_B(1, 0, 1); STAGE_A(1, 0, 1); STAGE_B(1, 1, 1);
    VMCNT(10);                       // tile0 B0,A0 retired (own wave)
    BAR(); SB0();
    LDAH(0, 0, a0);
    LDBH(0, 0, b0);

    for (int tt = 0; tt < NT; tt += 2) {
        TILE(tt,     0, a0,  b0,  a0n, b0n);
        TILE(tt + 1, 1, a0n, b0n, a0,  b0);
    }

    // ---- epilogue: C-write (C/D layout: col = lane&15, row = quad*4 + r)
#pragma unroll
    for (int mh = 0; mh < 2; ++mh)
#pragma unroll
        for (int nh = 0; nh < 2; ++nh)
#pragma unroll
            for (int mf = 0; mf < 4; ++mf)
#pragma unroll
                for (int nf = 0; nf < 2; ++nf)
#pragma unroll
                    for (int r = 0; r < 4; ++r) {
                        const int row = m0 + mh * 128 + wr * 64 + mf * 16 + quad * 4 + r;
                        const int col = n0 + nh * 128 + wc * 32 + nf * 16 + lq;
                        const float v = acc[mh][nh][mf][nf][r];
                        const size_t idx = (size_t)row * N + col;
                        if constexpr (sizeof(OutT) == 2) C[idx] = __float2bfloat16(v);
                        else                             C[idx] = v;
                    }
}

// ---------------- fused RMSNorm + partial RoPE (in place, strided) ----------------
__global__ __launch_bounds__(256) void norm_rope(bf16* __restrict__ buf,
                                                 const float* __restrict__ w,
                                                 const float* __restrict__ cosp,
                                                 const float* __restrict__ sinp,
                                                 int log2nh, int stride, int coloff) {
    const int lane = threadIdx.x & 63;
    const int wave = threadIdx.x >> 6;
    const int row  = blockIdx.x * 4 + wave;
    const int s    = row >> log2nh;
    const int hh   = row & ((1 << log2nh) - 1);
    bf16* p = buf + (size_t)s * stride + coloff + hh * DH;

    float x1 = __bfloat162float(p[lane]);
    float x2 = __bfloat162float(p[64 + lane]);

    float ss = x1 * x1 + x2 * x2;
#pragma unroll
    for (int off = 1; off < 64; off <<= 1) ss += __shfl_xor(ss, off);
    float rs = rsqrtf(ss * (1.0f / 128.0f) + RMS_EPS);

    float y1 = x1 * rs * w[lane];
    float y2 = x2 * rs * w[64 + lane];

    float partner = __shfl_xor(y1, 32);
    float c  = cosp[(size_t)s * ROTD + lane];
    float sn = sinp[(size_t)s * ROTD + lane];
    float rot = (lane < 32) ? (y1 * c - partner * sn) : (y1 * c + partner * sn);

    p[lane]      = __float2bfloat16(rot);
    p[64 + lane] = __float2bfloat16(y2);
}

// ---------------- V transpose: qkv V cols -> vt(NKV*DH, S) ----------------
__global__ __launch_bounds__(256) void transpose_v(const bf16* __restrict__ v,
                                                   bf16* __restrict__ vt,
                                                   int stride, int colofs) {
    __shared__ bf16 t[32][65];
    const int c0 = blockIdx.x * 32;
    const int s0 = blockIdx.y * 64;
    {
        const int j  = threadIdx.x & 31;
        const int i0 = threadIdx.x >> 5;
#pragma unroll
        for (int p = 0; p < 8; ++p) {
            int si = p * 8 + i0;
            t[j][si] = v[(size_t)(s0 + si) * stride + colofs + c0 + j];
        }
    }
    __syncthreads();
    {
        const int ii = threadIdx.x & 63;
        const int j0 = threadIdx.x >> 6;
#pragma unroll
        for (int p = 0; p < 8; ++p) {
            int c = p * 4 + j0;
            vt[(size_t)(c0 + c) * S_LEN + s0 + ii] = t[c][ii];
        }
    }
}

// ---------------- block-cooperative MFMA flash attention (causal, GQA) ----------------
struct FlashSmem {
    bf16 Ks[64][KPITCH];    // keys x dh
    bf16 Vs[128][VPITCH];   // dh x keys
    bf16 Ps[4][16][VPITCH]; // per-wave P round-trip
};

static __device__ __forceinline__ void attn_qblock(int q0, int n_iter, int h, int kvh,
                                                   const bf16* __restrict__ QKV,
                                                   const bf16* __restrict__ VT,
                                                   bf16* __restrict__ O,
                                                   FlashSmem* sm) {
    const int tid  = threadIdx.x;
    const int lane = tid & 63;
    const int wave = tid >> 6;
    const int lq   = lane & 15;
    const int quad = lane >> 4;
    const int qr0  = q0 + wave * 16;

    bf16x8 qf[4];
    const bf16* qrow = QKV + (size_t)(qr0 + lq) * QKVW + h * DH + quad * 8;
#pragma unroll
    for (int i = 0; i < 4; ++i) {
        bf16x8 qv = *reinterpret_cast<const bf16x8*>(qrow + 32 * i);
#pragma unroll
        for (int j = 0; j < 8; ++j) {
            bf16 b = __builtin_bit_cast(bf16, (unsigned short)qv[j]);
            qv[j] = (short)__builtin_bit_cast(unsigned short,
                        __float2bfloat16(__bfloat162float(b) * ATT_SCALE));
        }
        qf[i] = qv;
    }

    f32x4 o[8];
#pragma unroll
    for (int t2 = 0; t2 < 8; ++t2) o[t2] = (f32x4){0.f, 0.f, 0.f, 0.f};
    float m_i[4], l_i[4];
#pragma unroll
    for (int r = 0; r < 4; ++r) { m_i[r] = -1e30f; l_i[r] = 0.f; }

    const bf16* kg = QKV + (size_t)(tid >> 2) * QKVW + KOFF + kvh * DH + (tid & 3) * 32;
    const bf16* vg = VT + (size_t)(kvh * DH + (tid >> 1)) * S_LEN + (tid & 1) * 32;
    bf16* ksl = &sm->Ks[tid >> 2][(tid & 3) * 32];
    bf16* vsl = &sm->Vs[tid >> 1][(tid & 1) * 32];
    bf16* pb  = &sm->Ps[wave][0][0];

    bf16x8 kreg[4], vreg[4];
#pragma unroll
    for (int c = 0; c < 4; ++c) {
        kreg[c] = *reinterpret_cast<const bf16x8*>(kg + 8 * c);
        vreg[c] = *reinterpret_cast<const bf16x8*>(vg + 8 * c);
    }

    for (int kt = 0; kt < n_iter; ++kt) {
        const int k0 = kt * 64;
#pragma unroll
        for (int c = 0; c < 4; ++c) {
            *reinterpret_cast<bf16x8*>(ksl + 8 * c) = kreg[c];
            *reinterpret_cast<bf16x8*>(vsl + 8 * c) = vreg[c];
        }
        __syncthreads();
        if (kt + 1 < n_iter) {
            const size_t kadv = (size_t)(kt + 1) * 64;
#pragma unroll
            for (int c = 0; c < 4; ++c) {
                kreg[c] = *reinterpret_cast<const bf16x8*>(kg + kadv * QKVW + 8 * c);
                vreg[c] = *reinterpret_cast<const bf16x8*>(vg + kadv + 8 * c);
            }
        }

        float p[4][4];
#pragma unroll
        for (int t = 0; t < 4; ++t) {
            f32x4 sacc = (f32x4){0.f, 0.f, 0.f, 0.f};
#pragma unroll
            for (int i = 0; i < 4; ++i) {
                bf16x8 kf = *reinterpret_cast<const bf16x8*>(&sm->Ks[t * 16 + lq][quad * 8 + 32 * i]);
                sacc = __builtin_amdgcn_mfma_f32_16x16x32_bf16(qf[i], kf, sacc, 0, 0, 0);
            }
#pragma unroll
            for (int r = 0; r < 4; ++r) {
                int qi = qr0 + quad * 4 + r;
                int ki = k0 + t * 16 + lq;
                p[t][r] = (ki > qi) ? -1e30f : sacc[r];
            }
        }

        float rowmax[4];
#pragma unroll
        for (int r = 0; r < 4; ++r)
            rowmax[r] = fmaxf(fmaxf(p[0][r], p[1][r]), fmaxf(p[2][r], p[3][r]));
#pragma unroll
        for (int off = 1; off < 16; off <<= 1)
#pragma unroll
            for (int r = 0; r < 4; ++r) rowmax[r] = fmaxf(rowmax[r], __shfl_xor(rowmax[r], off));

        float alpha[4];
#pragma unroll
        for (int r = 0; r < 4; ++r) {
            float mn = fmaxf(m_i[r], rowmax[r]);
            alpha[r] = __expf(m_i[r] - mn);
            m_i[r] = mn;
        }
#pragma unroll
        for (int t = 0; t < 4; ++t)
#pragma unroll
            for (int r = 0; r < 4; ++r) p[t][r] = __expf(p[t][r] - m_i[r]);

        float rsum[4];
#pragma unroll
        for (int r = 0; r < 4; ++r) rsum[r] = (p[0][r] + p[1][r]) + (p[2][r] + p[3][r]);
#pragma unroll
        for (int off = 1; off < 16; off <<= 1)
#pragma unroll
            for (int r = 0; r < 4; ++r) rsum[r] += __shfl_xor(rsum[r], off);
#pragma unroll
        for (int r = 0; r < 4; ++r) l_i[r] = l_i[r] * alpha[r] + rsum[r];

#pragma unroll
        for (int t = 0; t < 4; ++t)
#pragma unroll
            for (int r = 0; r < 4; ++r)
                pb[(quad * 4 + r) * VPITCH + t * 16 + lq] = __float2bfloat16(p[t][r]);
        __threadfence_block();

#pragma unroll
        for (int t2 = 0; t2 < 8; ++t2)
#pragma unroll
            for (int r = 0; r < 4; ++r) o[t2][r] *= alpha[r];

#pragma unroll
        for (int hh = 0; hh < 2; ++hh) {
            bf16x8 pa = *reinterpret_cast<const bf16x8*>(pb + lq * VPITCH + hh * 32 + quad * 8);
#pragma unroll
            for (int t2 = 0; t2 < 8; ++t2) {
                bf16x8 vf = *reinterpret_cast<const bf16x8*>(&sm->Vs[t2 * 16 + lq][hh * 32 + quad * 8]);
                o[t2] = __builtin_amdgcn_mfma_f32_16x16x32_bf16(pa, vf, o[t2], 0, 0, 0);
            }
        }
        __syncthreads();
    }

#pragma unroll
    for (int r = 0; r < 4; ++r) l_i[r] = 1.0f / l_i[r];
#pragma unroll
    for (int t2 = 0; t2 < 8; ++t2)
#pragma unroll
        for (int r = 0; r < 4; ++r)
            O[(size_t)(qr0 + quad * 4 + r) * (NH * DH) + h * DH + t2 * 16 + lq] =
                __float2bfloat16(o[t2][r] * l_i[r]);
}

__global__ __launch_bounds__(256) void flash_attn(const bf16* __restrict__ QKV,
                                                  const bf16* __restrict__ VT,
                                                  bf16* __restrict__ O) {
    __shared__ FlashSmem sm;
    const int b  = blockIdx.x;       // 0..511
    const int h  = b & 31;
    const int pr = b >> 5;           // 0..15
    const int kvh = h >> 2;
    attn_qblock((31 - pr) * 64, 32 - pr, h, kvh, QKV, VT, O, &sm);
    __syncthreads();
    attn_qblock(pr * 64,        pr + 1,  h, kvh, QKV, VT, O, &sm);
}

extern "C" void kernel_launch(void* const* d_in, const int* in_sizes, int n_in,
                              void* d_out, int out_size, void* d_ws, size_t ws_size,
                              hipStream_t stream) {
    const float* hs   = (const float*)d_in[0];
    const float* cosp = (const float*)d_in[1];
    const float* sinp = (const float*)d_in[2];
    const float* Wq   = (const float*)d_in[3];
    const float* Wk   = (const float*)d_in[4];
    const float* Wv   = (const float*)d_in[5];
    const float* Wo   = (const float*)d_in[6];
    const float* qw   = (const float*)d_in[7];
    const float* kw   = (const float*)d_in[8];
    float* out = (float*)d_out;

    char* ws = (char*)d_ws;
    size_t off = 0;
    auto carve = [&](size_t bytes) { char* p = ws + off; off += (bytes + 255) & ~(size_t)255; return p; };

    bf16* hsb  = (bf16*)carve((size_t)S_LEN * HIDDEN * 2);          // hidden bf16; reused as AO
    bf16* wqkv = (bf16*)carve((size_t)QKVW * HIDDEN * 2);           // fused [6144, 4096]
    bf16* wob  = (bf16*)carve((size_t)HIDDEN * NH * DH * 2);
    bf16* qkv  = (bf16*)carve((size_t)S_LEN * QKVW * 2);            // [S, 6144]
    bf16* vtb  = (bf16*)carve((size_t)NKV * DH * S_LEN * 2);

    // 1. casts
    cast_f32_bf16<<<(S_LEN * HIDDEN / 4 + 255) / 256, 256, 0, stream>>>(hs, (unsigned short*)hsb, S_LEN * HIDDEN / 4);
    cast_f32_bf16<<<(NH * DH * HIDDEN / 4 + 255) / 256, 256, 0, stream>>>(Wq, (unsigned short*)wqkv, NH * DH * HIDDEN / 4);
    cast_f32_bf16<<<(NKV * DH * HIDDEN / 4 + 255) / 256, 256, 0, stream>>>(Wk, (unsigned short*)(wqkv + (size_t)KOFF * HIDDEN), NKV * DH * HIDDEN / 4);
    cast_f32_bf16<<<(NKV * DH * HIDDEN / 4 + 255) / 256, 256, 0, stream>>>(Wv, (unsigned short*)(wqkv + (size_t)VOFF * HIDDEN), NKV * DH * HIDDEN / 4);
    cast_f32_bf16<<<(HIDDEN * NH * DH / 4 + 255) / 256, 256, 0, stream>>>(Wo, (unsigned short*)wob, HIDDEN * NH * DH / 4);

    // 2. fused QKV projection (256^2 8-phase, read-ahead)
    gemm256<bf16><<<dim3((S_LEN / 256) * (QKVW / 256)), 512, 0, stream>>>(hsb, wqkv, qkv, S_LEN, QKVW, HIDDEN);

    // 3. rmsnorm + rope in place on Q and K slices
    norm_rope<<<S_LEN * NH / 4, 256, 0, stream>>>(qkv, qw, cosp, sinp, 5, QKVW, 0);
    norm_rope<<<S_LEN * NKV / 4, 256, 0, stream>>>(qkv, kw, cosp, sinp, 3, QKVW, KOFF);

    // 4. V transpose
    transpose_v<<<dim3(NKV * DH / 32, S_LEN / 64), 256, 0, stream>>>(qkv, vtb, QKVW, VOFF);

    // 5. flash attention -> AO (reuse hsb)
    bf16* aob = hsb;
    flash_attn<<<512, 256, 0, stream>>>(qkv, vtb, aob);

    // 6. output projection (fp32 out, 256^2 8-phase, read-ahead)
    gemm256<float><<<dim3((S_LEN / 256) * (HIDDEN / 256)), 512, 0, stream>>>(aob, wob, out, S_LEN, HIDDEN, NH * DH);
}

// Round 4
// 539.691 us; speedup vs baseline: 3.1560x; 3.1560x over previous
//
#include <hip/hip_runtime.h>
#include <hip/hip_bf16.h>

typedef __attribute__((ext_vector_type(8))) short bf16x8;
typedef __attribute__((ext_vector_type(4))) float f32x4;
typedef __hip_bfloat16 bf16;

#define S_LEN 2048
#define HIDDEN 4096
#define NH 32
#define NKV 8
#define DH 128
#define ROTD 64
#define QKVW 6144              // fused QKV row width (32*128 + 8*128 + 8*128)
#define KOFF 4096              // K column offset in fused buffer
#define VOFF 5120              // V column offset
#define ATT_SCALE 0.08838834764831845f
#define RMS_EPS 1e-6f
#define KPITCH 136             // Ks row pitch (elems): 272B = 17*16 -> aligned, 2-way banks
#define VPITCH 72              // Vs/Ps row pitch: 144B = 9*16 -> aligned, 2-way banks

#define BAR() __builtin_amdgcn_s_barrier()
#define VMCNT(n) asm volatile("s_waitcnt vmcnt(" #n ")" ::: "memory")
#define LGKM(n)  asm volatile("s_waitcnt lgkmcnt(" #n ")" ::: "memory")

static __device__ __forceinline__ unsigned short f2bu(float f) {
    bf16 h = __float2bfloat16(f);
    return __builtin_bit_cast(unsigned short, h);
}

static __device__ __forceinline__ void load_lds_16(const bf16* g, bf16* l) {
    __builtin_amdgcn_global_load_lds((const __attribute__((address_space(1))) void*)g,
                                     (__attribute__((address_space(3))) void*)l, 16, 0, 0);
}

// ---------------- fp32 -> bf16 cast (vectorized float4) ----------------
__global__ __launch_bounds__(256) void cast_f32_bf16(const float* __restrict__ src,
                                                     unsigned short* __restrict__ dst, int n4) {
    int i = blockIdx.x * 256 + threadIdx.x;
    if (i >= n4) return;
    float4 v = reinterpret_cast<const float4*>(src)[i];
    ushort4 o;
    o.x = f2bu(v.x); o.y = f2bu(v.y); o.z = f2bu(v.z); o.w = f2bu(v.w);
    reinterpret_cast<ushort4*>(dst)[i] = o;
}

// ---------------- fp32 in-place add (split-K reduction) ----------------
__global__ __launch_bounds__(256) void add_f32(float* __restrict__ dst,
                                               const float* __restrict__ src, int n4) {
    int i = blockIdx.x * 256 + threadIdx.x;
    if (i >= n4) return;
    float4 a = reinterpret_cast<float4*>(dst)[i];
    float4 b = reinterpret_cast<const float4*>(src)[i];
    a.x += b.x; a.y += b.y; a.z += b.z; a.w += b.w;
    reinterpret_cast<float4*>(dst)[i] = a;
}

// ---------------- C[M,N] = A[M,K] @ B[N,K]^T ----------------
// 256x256 tile, BK=64, 8 waves (2M x 4N), 8-phase schedule (T2+T3+T4+T5):
//  - LDS: 2 dbuf x 2 half x [128][64] bf16 for A and B = 128 KiB
//  - swizzle: byte ^= (row&7)<<4 (involution; pre-swizzled global src, swizzled ds_read)
//  - staging: one half-tile (2 x global_load_lds_dwordx4) per phase, 3 half-tiles ahead
//  - vmcnt(6) only at tile boundaries (vmcnt(0) at the final two)
//  - optional split-K: blockIdx.y selects a K-slice of `ktiles` 64-wide tiles;
//    slice 0 writes C, slice 1 writes C2 (fp32 partial, reduced by add_f32)
// NOTE (round-2 lesson): do NOT add extra register fragment sets here; acc(128) +
// av/bv(64) is at the VGPR budget for 2 waves/EU — more sets spill to scratch
// (observed: WRITE_SIZE 24MB -> 820MB, 6x slowdown).
#define LDA_SUB(bufi, half) do {                                                        \
    const bf16* _ab = &As[bufi][half][0];                                               \
    _Pragma("unroll") for (int mf = 0; mf < 4; ++mf) {                                  \
        const int _r = arow + mf * 16;                                                  \
        _Pragma("unroll") for (int kk = 0; kk < 2; ++kk)                                \
            av[mf][kk] = *reinterpret_cast<const bf16x8*>(                              \
                _ab + (((_r << 6) + kk * 32 + quad * 8) ^ xorv));                       \
    } } while (0)

#define LDB_SUB(bufi, half, set) do {                                                   \
    const bf16* _bb = &Bs[bufi][half][0];                                               \
    _Pragma("unroll") for (int nf = 0; nf < 2; ++nf) {                                  \
        const int _r = brow + nf * 16;                                                  \
        _Pragma("unroll") for (int kk = 0; kk < 2; ++kk)                                \
            bv[set][nf][kk] = *reinterpret_cast<const bf16x8*>(                         \
                _bb + (((_r << 6) + kk * 32 + quad * 8) ^ xorv));                       \
    } } while (0)

#define MMQ(mh, nh, set) do {                                                           \
    _Pragma("unroll") for (int mf = 0; mf < 4; ++mf)                                    \
    _Pragma("unroll") for (int nf = 0; nf < 2; ++nf)                                    \
    _Pragma("unroll") for (int kk = 0; kk < 2; ++kk)                                    \
        acc[mh][nh][mf][nf] = __builtin_amdgcn_mfma_f32_16x16x32_bf16(                  \
            av[mf][kk], bv[set][nf][kk], acc[mh][nh][mf][nf], 0, 0, 0);                 \
    } while (0)

#define STAGE_A(bufi, half, tau) do {                                                   \
    const bf16* _s = Abase + (size_t)(half) * 128 * K + (size_t)(tau) * 64;             \
    load_lds_16(_s + sro0, &As[bufi][half][e0]);                                        \
    load_lds_16(_s + sro1, &As[bufi][half][e1]); } while (0)

#define STAGE_B(bufi, half, tau) do {                                                   \
    const bf16* _s = Bbase + (size_t)(half) * 128 * K + (size_t)(tau) * 64;             \
    load_lds_16(_s + sro0, &Bs[bufi][half][e0]);                                        \
    load_lds_16(_s + sro1, &Bs[bufi][half][e1]); } while (0)

template <typename OutT>
__global__ __launch_bounds__(512, 2) void gemm256(const bf16* __restrict__ A,
                                                  const bf16* __restrict__ B,
                                                  OutT* __restrict__ C,
                                                  OutT* __restrict__ C2,
                                                  int M, int N, int K, int ktiles) {
    __shared__ bf16 As[2][2][128 * 64];
    __shared__ bf16 Bs[2][2][128 * 64];

    const int tid  = threadIdx.x;
    const int lane = tid & 63;
    const int lq   = lane & 15;
    const int quad = lane >> 4;
    const int wave = tid >> 6;
    const int wr   = wave >> 2;      // 0..1 (M)
    const int wc   = wave & 3;       // 0..3 (N)

    // XCD-aware block swizzle (grid.x here is a multiple of 8)
    const int nwg = gridDim.x;
    const int cpx = nwg >> 3;
    const int wg  = (blockIdx.x & 7) * cpx + (blockIdx.x >> 3);
    const int ntn = N >> 8;
    const int m0  = (wg / ntn) << 8;
    const int n0  = (wg % ntn) << 8;
    const int ksl = blockIdx.y;      // K-slice index (split-K)

    const int NT = ktiles;           // 64-wide K tiles this slice (even, >= 4)

    // ---- staging thread-constants: dest byte d -> pre-swizzled source offset o
    const int d0 = tid * 16;
    const int d1 = 8192 + tid * 16;
    const int o0 = d0 ^ (((d0 >> 7) & 7) << 4);
    const int o1 = d1 ^ (((d1 >> 7) & 7) << 4);
    const int e0 = d0 >> 1;          // LDS dest element offset (linear)
    const int e1 = d1 >> 1;
    const size_t sro0 = (size_t)((o0 >> 1) >> 6) * K + ((o0 >> 1) & 63);
    const size_t sro1 = (size_t)((o1 >> 1) >> 6) * K + ((o1 >> 1) & 63);
    const bf16* Abase = A + (size_t)m0 * K + (size_t)ksl * ktiles * 64;
    const bf16* Bbase = B + (size_t)n0 * K + (size_t)ksl * ktiles * 64;
    OutT* __restrict__ Cw = ksl ? C2 : C;

    // ---- fragment read constants
    const int arow = wr * 64 + lq;   // + mf*16  (row within A half)
    const int brow = wc * 32 + lq;   // + nf*16  (row within B half)
    const int xorv = (lq & 7) << 3;  // element-offset swizzle ((row&7)<<4 bytes)

    f32x4  acc[2][2][4][2] = {};
    bf16x8 av[4][2];                 // A-subtile for current mh
    bf16x8 bv[2][2][2];              // B-subtiles for nh=0 and nh=1 (both kept live)

    // ---- prologue: stage 7 half-tiles in sigma order, drain tile 0
    STAGE_B(0, 0, 0); STAGE_A(0, 0, 0); STAGE_B(0, 1, 0); STAGE_A(0, 1, 0);
    STAGE_B(1, 0, 1); STAGE_A(1, 0, 1); STAGE_B(1, 1, 1);
    VMCNT(6);
    BAR();

    for (int t = 0; t < NT; ++t) {
        const int buf = t & 1;

        // ---- p0: quadrant (0,0)
        LDA_SUB(buf, 0);
        LDB_SUB(buf, 0, 0);
        if (t + 1 < NT) STAGE_A(buf ^ 1, 1, t + 1);
        LGKM(8);
        BAR();
        LGKM(0);
        __builtin_amdgcn_s_setprio(1);
        MMQ(0, 0, 0);
        __builtin_amdgcn_s_setprio(0);
        BAR();

        // ---- p1: quadrant (0,1)
        LDB_SUB(buf, 1, 1);
        if (t + 2 < NT) STAGE_B(buf, 0, t + 2);
        BAR();
        LGKM(0);
        __builtin_amdgcn_s_setprio(1);
        MMQ(0, 1, 1);
        __builtin_amdgcn_s_setprio(0);
        BAR();

        // ---- p2: quadrant (1,1)
        LDA_SUB(buf, 1);
        if (t + 2 < NT) STAGE_A(buf, 0, t + 2);
        BAR();
        LGKM(0);
        __builtin_amdgcn_s_setprio(1);
        MMQ(1, 1, 1);
        __builtin_amdgcn_s_setprio(0);
        BAR();

        // ---- p3: quadrant (1,0)  (A from p2, B set 0 from p0 -- registers only)
        if (t + 2 < NT) STAGE_B(buf, 1, t + 2);
        BAR();
        __builtin_amdgcn_s_setprio(1);
        MMQ(1, 0, 0);
        __builtin_amdgcn_s_setprio(0);
        if (t < NT - 2) { VMCNT(6); } else { VMCNT(0); }   // boundary: next tile resident
        BAR();
    }

    // ---- epilogue: C-write (C/D layout: col = lane&15, row = quad*4 + r)
#pragma unroll
    for (int mh = 0; mh < 2; ++mh)
#pragma unroll
        for (int nh = 0; nh < 2; ++nh)
#pragma unroll
            for (int mf = 0; mf < 4; ++mf)
#pragma unroll
                for (int nf = 0; nf < 2; ++nf)
#pragma unroll
                    for (int r = 0; r < 4; ++r) {
                        const int row = m0 + mh * 128 + wr * 64 + mf * 16 + quad * 4 + r;
                        const int col = n0 + nh * 128 + wc * 32 + nf * 16 + lq;
                        const float v = acc[mh][nh][mf][nf][r];
                        const size_t idx = (size_t)row * N + col;
                        if constexpr (sizeof(OutT) == 2) Cw[idx] = __float2bfloat16(v);
                        else                             Cw[idx] = v;
                    }
}

// ---------------- fused RMSNorm + partial RoPE (in place, strided) ----------------
__global__ __launch_bounds__(256) void norm_rope(bf16* __restrict__ buf,
                                                 const float* __restrict__ w,
                                                 const float* __restrict__ cosp,
                                                 const float* __restrict__ sinp,
                                                 int log2nh, int stride, int coloff) {
    const int lane = threadIdx.x & 63;
    const int wave = threadIdx.x >> 6;
    const int row  = blockIdx.x * 4 + wave;
    const int s    = row >> log2nh;
    const int hh   = row & ((1 << log2nh) - 1);
    bf16* p = buf + (size_t)s * stride + coloff + hh * DH;

    float x1 = __bfloat162float(p[lane]);
    float x2 = __bfloat162float(p[64 + lane]);

    float ss = x1 * x1 + x2 * x2;
#pragma unroll
    for (int off = 1; off < 64; off <<= 1) ss += __shfl_xor(ss, off);
    float rs = rsqrtf(ss * (1.0f / 128.0f) + RMS_EPS);

    float y1 = x1 * rs * w[lane];
    float y2 = x2 * rs * w[64 + lane];

    float partner = __shfl_xor(y1, 32);
    float c  = cosp[(size_t)s * ROTD + lane];
    float sn = sinp[(size_t)s * ROTD + lane];
    float rot = (lane < 32) ? (y1 * c - partner * sn) : (y1 * c + partner * sn);

    p[lane]      = __float2bfloat16(rot);
    p[64 + lane] = __float2bfloat16(y2);
}

// ---------------- V transpose: qkv V cols -> vt(NKV*DH, S) ----------------
__global__ __launch_bounds__(256) void transpose_v(const bf16* __restrict__ v,
                                                   bf16* __restrict__ vt,
                                                   int stride, int colofs) {
    __shared__ bf16 t[32][65];
    const int c0 = blockIdx.x * 32;
    const int s0 = blockIdx.y * 64;
    {
        const int j  = threadIdx.x & 31;
        const int i0 = threadIdx.x >> 5;
#pragma unroll
        for (int p = 0; p < 8; ++p) {
            int si = p * 8 + i0;
            t[j][si] = v[(size_t)(s0 + si) * stride + colofs + c0 + j];
        }
    }
    __syncthreads();
    {
        const int ii = threadIdx.x & 63;
        const int j0 = threadIdx.x >> 6;
#pragma unroll
        for (int p = 0; p < 8; ++p) {
            int c = p * 4 + j0;
            vt[(size_t)(c0 + c) * S_LEN + s0 + ii] = t[c][ii];
        }
    }
}

// ---------------- block-cooperative MFMA flash attention (causal, GQA) ----------------
struct FlashSmem {
    bf16 Ks[64][KPITCH];    // keys x dh
    bf16 Vs[128][VPITCH];   // dh x keys
    bf16 Ps[4][16][VPITCH]; // per-wave P round-trip
};

static __device__ __forceinline__ void attn_qblock(int q0, int n_iter, int h, int kvh,
                                                   const bf16* __restrict__ QKV,
                                                   const bf16* __restrict__ VT,
                                                   bf16* __restrict__ O,
                                                   FlashSmem* sm) {
    const int tid  = threadIdx.x;
    const int lane = tid & 63;
    const int wave = tid >> 6;
    const int lq   = lane & 15;
    const int quad = lane >> 4;
    const int qr0  = q0 + wave * 16;

    bf16x8 qf[4];
    const bf16* qrow = QKV + (size_t)(qr0 + lq) * QKVW + h * DH + quad * 8;
#pragma unroll
    for (int i = 0; i < 4; ++i) {
        bf16x8 qv = *reinterpret_cast<const bf16x8*>(qrow + 32 * i);
#pragma unroll
        for (int j = 0; j < 8; ++j) {
            bf16 b = __builtin_bit_cast(bf16, (unsigned short)qv[j]);
            qv[j] = (short)__builtin_bit_cast(unsigned short,
                        __float2bfloat16(__bfloat162float(b) * ATT_SCALE));
        }
        qf[i] = qv;
    }

    f32x4 o[8];
#pragma unroll
    for (int t2 = 0; t2 < 8; ++t2) o[t2] = (f32x4){0.f, 0.f, 0.f, 0.f};
    float m_i[4], l_i[4];
#pragma unroll
    for (int r = 0; r < 4; ++r) { m_i[r] = -1e30f; l_i[r] = 0.f; }

    const bf16* kg = QKV + (size_t)(tid >> 2) * QKVW + KOFF + kvh * DH + (tid & 3) * 32;
    const bf16* vg = VT + (size_t)(kvh * DH + (tid >> 1)) * S_LEN + (tid & 1) * 32;
    bf16* ksl = &sm->Ks[tid >> 2][(tid & 3) * 32];
    bf16* vsl = &sm->Vs[tid >> 1][(tid & 1) * 32];
    bf16* pb  = &sm->Ps[wave][0][0];

    bf16x8 kreg[4], vreg[4];
#pragma unroll
    for (int c = 0; c < 4; ++c) {
        kreg[c] = *reinterpret_cast<const bf16x8*>(kg + 8 * c);
        vreg[c] = *reinterpret_cast<const bf16x8*>(vg + 8 * c);
    }

    for (int kt = 0; kt < n_iter; ++kt) {
        const int k0 = kt * 64;
#pragma unroll
        for (int c = 0; c < 4; ++c) {
            *reinterpret_cast<bf16x8*>(ksl + 8 * c) = kreg[c];
            *reinterpret_cast<bf16x8*>(vsl + 8 * c) = vreg[c];
        }
        __syncthreads();
        if (kt + 1 < n_iter) {
            const size_t kadv = (size_t)(kt + 1) * 64;
#pragma unroll
            for (int c = 0; c < 4; ++c) {
                kreg[c] = *reinterpret_cast<const bf16x8*>(kg + kadv * QKVW + 8 * c);
                vreg[c] = *reinterpret_cast<const bf16x8*>(vg + kadv + 8 * c);
            }
        }

        float p[4][4];
#pragma unroll
        for (int t = 0; t < 4; ++t) {
            f32x4 sacc = (f32x4){0.f, 0.f, 0.f, 0.f};
#pragma unroll
            for (int i = 0; i < 4; ++i) {
                bf16x8 kf = *reinterpret_cast<const bf16x8*>(&sm->Ks[t * 16 + lq][quad * 8 + 32 * i]);
                sacc = __builtin_amdgcn_mfma_f32_16x16x32_bf16(qf[i], kf, sacc, 0, 0, 0);
            }
#pragma unroll
            for (int r = 0; r < 4; ++r) {
                int qi = qr0 + quad * 4 + r;
                int ki = k0 + t * 16 + lq;
                p[t][r] = (ki > qi) ? -1e30f : sacc[r];
            }
        }

        float rowmax[4];
#pragma unroll
        for (int r = 0; r < 4; ++r)
            rowmax[r] = fmaxf(fmaxf(p[0][r], p[1][r]), fmaxf(p[2][r], p[3][r]));
#pragma unroll
        for (int off = 1; off < 16; off <<= 1)
#pragma unroll
            for (int r = 0; r < 4; ++r) rowmax[r] = fmaxf(rowmax[r], __shfl_xor(rowmax[r], off));

        float alpha[4];
#pragma unroll
        for (int r = 0; r < 4; ++r) {
            float mn = fmaxf(m_i[r], rowmax[r]);
            alpha[r] = __expf(m_i[r] - mn);
            m_i[r] = mn;
        }
#pragma unroll
        for (int t = 0; t < 4; ++t)
#pragma unroll
            for (int r = 0; r < 4; ++r) p[t][r] = __expf(p[t][r] - m_i[r]);

        float rsum[4];
#pragma unroll
        for (int r = 0; r < 4; ++r) rsum[r] = (p[0][r] + p[1][r]) + (p[2][r] + p[3][r]);
#pragma unroll
        for (int off = 1; off < 16; off <<= 1)
#pragma unroll
            for (int r = 0; r < 4; ++r) rsum[r] += __shfl_xor(rsum[r], off);
#pragma unroll
        for (int r = 0; r < 4; ++r) l_i[r] = l_i[r] * alpha[r] + rsum[r];

#pragma unroll
        for (int t = 0; t < 4; ++t)
#pragma unroll
            for (int r = 0; r < 4; ++r)
                pb[(quad * 4 + r) * VPITCH + t * 16 + lq] = __float2bfloat16(p[t][r]);
        __threadfence_block();

#pragma unroll
        for (int t2 = 0; t2 < 8; ++t2)
#pragma unroll
            for (int r = 0; r < 4; ++r) o[t2][r] *= alpha[r];

#pragma unroll
        for (int hh = 0; hh < 2; ++hh) {
            bf16x8 pa = *reinterpret_cast<const bf16x8*>(pb + lq * VPITCH + hh * 32 + quad * 8);
#pragma unroll
            for (int t2 = 0; t2 < 8; ++t2) {
                bf16x8 vf = *reinterpret_cast<const bf16x8*>(&sm->Vs[t2 * 16 + lq][hh * 32 + quad * 8]);
                o[t2] = __builtin_amdgcn_mfma_f32_16x16x32_bf16(pa, vf, o[t2], 0, 0, 0);
            }
        }
        __syncthreads();
    }

#pragma unroll
    for (int r = 0; r < 4; ++r) l_i[r] = 1.0f / l_i[r];
#pragma unroll
    for (int t2 = 0; t2 < 8; ++t2)
#pragma unroll
        for (int r = 0; r < 4; ++r)
            O[(size_t)(qr0 + quad * 4 + r) * (NH * DH) + h * DH + t2 * 16 + lq] =
                __float2bfloat16(o[t2][r] * l_i[r]);
}

__global__ __launch_bounds__(256) void flash_attn(const bf16* __restrict__ QKV,
                                                  const bf16* __restrict__ VT,
                                                  bf16* __restrict__ O) {
    __shared__ FlashSmem sm;
    const int b  = blockIdx.x;       // 0..511
    const int h  = b & 31;
    const int pr = b >> 5;           // 0..15
    const int kvh = h >> 2;
    attn_qblock((31 - pr) * 64, 32 - pr, h, kvh, QKV, VT, O, &sm);
    __syncthreads();
    attn_qblock(pr * 64,        pr + 1,  h, kvh, QKV, VT, O, &sm);
}

extern "C" void kernel_launch(void* const* d_in, const int* in_sizes, int n_in,
                              void* d_out, int out_size, void* d_ws, size_t ws_size,
                              hipStream_t stream) {
    const float* hs   = (const float*)d_in[0];
    const float* cosp = (const float*)d_in[1];
    const float* sinp = (const float*)d_in[2];
    const float* Wq   = (const float*)d_in[3];
    const float* Wk   = (const float*)d_in[4];
    const float* Wv   = (const float*)d_in[5];
    const float* Wo   = (const float*)d_in[6];
    const float* qw   = (const float*)d_in[7];
    const float* kw   = (const float*)d_in[8];
    float* out = (float*)d_out;

    char* ws = (char*)d_ws;
    size_t off = 0;
    auto carve = [&](size_t bytes) { char* p = ws + off; off += (bytes + 255) & ~(size_t)255; return p; };

    bf16* hsb  = (bf16*)carve((size_t)S_LEN * HIDDEN * 2);          // hidden bf16; reused as AO
    bf16* wqkv = (bf16*)carve((size_t)QKVW * HIDDEN * 2);           // fused [6144, 4096]; reused as split-K partial
    bf16* wob  = (bf16*)carve((size_t)HIDDEN * NH * DH * 2);
    bf16* qkv  = (bf16*)carve((size_t)S_LEN * QKVW * 2);            // [S, 6144]
    bf16* vtb  = (bf16*)carve((size_t)NKV * DH * S_LEN * 2);

    // 1. casts
    cast_f32_bf16<<<(S_LEN * HIDDEN / 4 + 255) / 256, 256, 0, stream>>>(hs, (unsigned short*)hsb, S_LEN * HIDDEN / 4);
    cast_f32_bf16<<<(NH * DH * HIDDEN / 4 + 255) / 256, 256, 0, stream>>>(Wq, (unsigned short*)wqkv, NH * DH * HIDDEN / 4);
    cast_f32_bf16<<<(NKV * DH * HIDDEN / 4 + 255) / 256, 256, 0, stream>>>(Wk, (unsigned short*)(wqkv + (size_t)KOFF * HIDDEN), NKV * DH * HIDDEN / 4);
    cast_f32_bf16<<<(NKV * DH * HIDDEN / 4 + 255) / 256, 256, 0, stream>>>(Wv, (unsigned short*)(wqkv + (size_t)VOFF * HIDDEN), NKV * DH * HIDDEN / 4);
    cast_f32_bf16<<<(HIDDEN * NH * DH / 4 + 255) / 256, 256, 0, stream>>>(Wo, (unsigned short*)wob, HIDDEN * NH * DH / 4);

    // 2. fused QKV projection (256^2 8-phase, 192 blocks, full K)
    gemm256<bf16><<<dim3((S_LEN / 256) * (QKVW / 256), 1), 512, 0, stream>>>(
        hsb, wqkv, qkv, qkv, S_LEN, QKVW, HIDDEN, HIDDEN / 64);

    // 3. rmsnorm + rope in place on Q and K slices
    norm_rope<<<S_LEN * NH / 4, 256, 0, stream>>>(qkv, qw, cosp, sinp, 5, QKVW, 0);
    norm_rope<<<S_LEN * NKV / 4, 256, 0, stream>>>(qkv, kw, cosp, sinp, 3, QKVW, KOFF);

    // 4. V transpose
    transpose_v<<<dim3(NKV * DH / 32, S_LEN / 64), 256, 0, stream>>>(qkv, vtb, QKVW, VOFF);

    // 5. flash attention -> AO (reuse hsb)
    bf16* aob = hsb;
    flash_attn<<<512, 256, 0, stream>>>(qkv, vtb, aob);

    // 6. output projection, split-K x2 (256 blocks = full CU fill).
    //    Slice 0 -> out, slice 1 -> fp32 partial in the dead wqkv region (33.5MB <= 50MB).
    float* p1 = (float*)wqkv;
    gemm256<float><<<dim3((S_LEN / 256) * (HIDDEN / 256), 2), 512, 0, stream>>>(
        aob, wob, out, p1, S_LEN, HIDDEN, NH * DH, (NH * DH) / 2 / 64);

    // 7. split-K reduction: out += p1
    add_f32<<<(S_LEN * HIDDEN / 4 + 255) / 256, 256, 0, stream>>>(out, p1, S_LEN * HIDDEN / 4);
}